// Round 5
// baseline (508.161 us; speedup 1.0000x reference)
//
#include <hip/hip_runtime.h>
#include <hip/hip_bf16.h>

#define EPS 1e-5f

typedef unsigned int u32;
typedef unsigned short u16;
typedef __attribute__((ext_vector_type(8))) short bf16x8;
typedef __attribute__((ext_vector_type(4))) float f32x4;

__device__ __forceinline__ u32 f2bf(float f) {
    u32 u = __float_as_uint(f);
    u += 0x7FFFu + ((u >> 16) & 1u);      // RNE
    return u >> 16;
}
__device__ __forceinline__ float bf2f(u32 h) {
    return __uint_as_float(h << 16);
}

__device__ __forceinline__ void gload16(const void* g, void* l) {
    __builtin_amdgcn_global_load_lds((const __attribute__((address_space(1))) void*)g,
                                     (__attribute__((address_space(3))) void*)l, 16, 0, 0);
}

// ---- K1: fused stats + bf16 transpose ----
// Per-(b,c) partial sums go to indexed slots (no atomics, no zero-init needed).
__global__ __launch_bounds__(256) void k1_tstats(const float* __restrict__ x,
                                                 u16* __restrict__ xT,
                                                 float* __restrict__ gS,
                                                 float* __restrict__ gSS) {
    int b  = blockIdx.y;
    int c0 = (blockIdx.x & 7) * 32;
    int lgrp = blockIdx.x >> 3;
    int l0 = lgrp * 512;
    int t  = threadIdx.x;
    __shared__ __align__(16) u16 T[512 * 32];   // [l][c] bf16, 64 B/row, swizzled slots

    int crow = t >> 3;                          // 0..31 : fixed c-row per thread
    int f4b  = t & 7;
    const float* xr = x + ((size_t)(b * 256 + c0 + crow)) * 4096 + l0;
    int cb   = (2 * crow) & 15;                 // byte-in-slot
    int slot = crow >> 3;                       // logical 16B slot of this c
    float s = 0.f, ss = 0.f;
#pragma unroll
    for (int i = 0; i < 16; ++i) {
        int f4 = f4b + 8 * i;                   // 0..127 float4 within row
        float4 v = *(const float4*)(xr + 4 * f4);
        s  += v.x + v.y + v.z + v.w;
        ss += v.x * v.x + v.y * v.y + v.z * v.z + v.w * v.w;
        char* base = (char*)T + f4 * 256 + (((slot ^ (f4 & 3)) << 4) | cb);
        *(u16*)(base      ) = (u16)f2bf(v.x);
        *(u16*)(base +  64) = (u16)f2bf(v.y);
        *(u16*)(base + 128) = (u16)f2bf(v.z);
        *(u16*)(base + 192) = (u16)f2bf(v.w);
    }
    s += __shfl_xor(s, 1, 64); ss += __shfl_xor(ss, 1, 64);
    s += __shfl_xor(s, 2, 64); ss += __shfl_xor(ss, 2, 64);
    s += __shfl_xor(s, 4, 64); ss += __shfl_xor(ss, 4, 64);
    if ((t & 7) == 0) {
        int idx = ((b * 256 + c0 + crow) << 3) + lgrp;
        gS [idx] = s;
        gSS[idx] = ss;
    }
    __syncthreads();
    u16* xrow = xT + ((size_t)b * 4096 + l0) * 256 + c0;
    int sslot = t & 3;
#pragma unroll
    for (int k = 0; k < 8; ++k) {
        int ll  = k * 64 + (t >> 2);            // 0..511
        int key = (ll >> 2) & 3;
        uint4 vv = *(const uint4*)((const char*)T + ll * 64 + ((sslot ^ key) << 4));
        *(uint4*)(xrow + (size_t)ll * 256 + 8 * sslot) = vv;
    }
}

// ---- K2: softmax-weight prep; wch staged in LDS via float4 ----
__global__ __launch_bounds__(256) void k2_prep(const float* __restrict__ wch,
                                               const float* __restrict__ wdn,
                                               const float* __restrict__ gS,
                                               const float* __restrict__ gSS,
                                               u16* __restrict__ Wc,
                                               float* __restrict__ bias,
                                               float* __restrict__ gsum,
                                               float* __restrict__ gss) {
    int b = blockIdx.x, t = threadIdx.x;
    __shared__ float swch[64 * 256];            // 64 KB
    __shared__ float sinv[256], ssc[256], smn[256], smxs[256];
#pragma unroll
    for (int k = 0; k < 16; ++k)
        *(float4*)&swch[k * 1024 + t * 4] = *(const float4*)&wch[k * 1024 + t * 4];
    __syncthreads();
    {
        int c = t;
        float mx = -1e30f;
        for (int o = 0; o < 64; ++o) mx = fmaxf(mx, swch[o * 256 + c]);
        float sum = 0.f;
        for (int o = 0; o < 64; ++o) sum += __expf(swch[o * 256 + c] - mx);
        smxs[c] = mx; sinv[c] = 1.f / sum;
        float S = 0.f, Q = 0.f;
#pragma unroll
        for (int k = 0; k < 8; ++k) {
            S += gS [((b * 256 + c) << 3) + k];
            Q += gSS[((b * 256 + c) << 3) + k];
        }
        float m = S * (1.f / 4096.f);
        float v = fmaxf(Q * (1.f / 4096.f) - m * m, 0.f);
        ssc[c] = rsqrtf(v + EPS);
        smn[c] = m;
    }
    __syncthreads();

    int lane = t & 63, w = t >> 6;
    int sub = lane >> 5, li = lane & 31;     // half-wave id, lane-in-half
    int c8 = li * 8;
    u16* Wb = Wc + (size_t)b * 128 * 256;
#pragma unroll 4
    for (int j = 0; j < 16; ++j) {
        int r = j * 8 + w * 2 + sub;         // 0..127
        float p = 0.f;
        u32 packed[4];
#pragma unroll
        for (int e = 0; e < 4; ++e) {
            u32 lohi[2];
#pragma unroll
            for (int h = 0; h < 2; ++h) {
                int c = c8 + 2 * e + h;
                float wv;
                if (r < 64)       wv = __expf(swch[r * 256 + c] - smxs[c]) * sinv[c];
                else if (r < 112) wv = wdn[(r - 64) * 256 + c];
                else              wv = 0.f;
                u32 hb = f2bf(wv * ssc[c]);
                lohi[h] = hb;
                p += bf2f(hb) * smn[c];
            }
            packed[e] = lohi[0] | (lohi[1] << 16);
        }
        *(uint4*)&Wb[r * 256 + c8] = *(uint4*)packed;
#pragma unroll
        for (int off = 1; off <= 16; off <<= 1) p += __shfl_xor(p, off, 64);
        if (li == 0) bias[b * 128 + r] = -p;
    }
    if (t < 48) { gsum[b * 48 + t] = 0.f; gss[b * 48 + t] = 0.f; }
}

// ---- K3: MFMA GEMM, gload_lds staging (pre-swizzled source), XCD-swizzled grid ----
__global__ __launch_bounds__(256, 4) void k3_main(const u16* __restrict__ xT,
                                                  const u16* __restrict__ Wc,
                                                  const float* __restrict__ bias,
                                                  u16* __restrict__ imgw,
                                                  u16* __restrict__ skipw,
                                                  float* __restrict__ gsum,
                                                  float* __restrict__ gss) {
    // XCD-aware bijective swizzle: 2048 blocks, 8 XCDs, 256 per XCD.
    // XCD x gets contiguous swz range [x*256, (x+1)*256) = batches b = x*8..x*8+7
    // (each b's Wc = 64 KB -> 512 KB of Wc per XCD-L2, reused by 32 lt-blocks).
    int orig = blockIdx.x;
    int swz  = (orig & 7) * 256 + (orig >> 3);
    int b  = swz >> 5;            // 0..63
    int lt = swz & 31;            // 0..31  (128-wide l tiles)
    int n0blk = lt * 128;
    int t = threadIdx.x;
    int w = t >> 6, u = t & 63;
    int lane16 = u & 15, q = u >> 4;
    int m0  = (w & 1) * 64;       // wave m-quadrant
    int n0w = (w >> 1) * 64;      // wave n-quadrant

    __shared__ __align__(16) u16 Wl[128 * 64];   // 16 KB: [row][128B], content slot-swizzled
    __shared__ __align__(16) u16 Xl[128 * 64];   // 16 KB
    __shared__ float sbias[128];

    if (t < 128) sbias[t] = bias[b * 128 + t];

    f32x4 acc[4][4];
#pragma unroll
    for (int mt = 0; mt < 4; ++mt)
#pragma unroll
        for (int nt = 0; nt < 4; ++nt) acc[mt][nt] = (f32x4){0.f, 0.f, 0.f, 0.f};

    const char* Wb = (const char*)(Wc + (size_t)b * 128 * 256);
    const char* xb = (const char*)(xT + ((size_t)b * 4096 + n0blk) * 256);

    // Staging: per wave-call 8 rows x 8 slots of 16B (1 KB), LDS dest linear,
    // global source slot pre-swizzled (slot s ^ (r&7)).
    int r_lane = u >> 3;                    // 0..7
    int gswz   = ((u & 7) ^ r_lane) << 4;   // swizzled 16B-slot byte offset in 128B chunk
    int swz16  = (lane16 & 7) << 4;

    for (int cc = 0; cc < 4; ++cc) {
        if (cc) __syncthreads();
        int c0b = cc << 7;                  // byte offset of 64-c chunk within 512B row
#pragma unroll
        for (int k = 0; k < 4; ++k) {
            int R0 = 32 * w + 8 * k;
            gload16(Wb + (size_t)(R0 + r_lane) * 512 + c0b + gswz, (char*)Wl + R0 * 128);
        }
#pragma unroll
        for (int k = 0; k < 4; ++k) {
            int R0 = 32 * w + 8 * k;
            gload16(xb + (size_t)(R0 + r_lane) * 512 + c0b + gswz, (char*)Xl + R0 * 128);
        }
        __syncthreads();
#pragma unroll
        for (int kk = 0; kk < 2; ++kk) {
            int kob = (kk * 64 + q * 16) ^ swz16;
            bf16x8 af[4], bfr[4];
#pragma unroll
            for (int nt = 0; nt < 4; ++nt)
                bfr[nt] = *(const bf16x8*)((const char*)Xl + (n0w + 16 * nt + lane16) * 128 + kob);
#pragma unroll
            for (int mt = 0; mt < 4; ++mt)
                af[mt] = *(const bf16x8*)((const char*)Wl + (m0 + 16 * mt + lane16) * 128 + kob);
#pragma unroll
            for (int mt = 0; mt < 4; ++mt)
#pragma unroll
                for (int nt = 0; nt < 4; ++nt)
                    acc[mt][nt] = __builtin_amdgcn_mfma_f32_16x16x32_bf16(af[mt], bfr[nt], acc[mt][nt], 0, 0, 0);
        }
    }
    __syncthreads();

    int jb48 = b * 48;
    if (m0 == 0) {
        int g2 = q >> 1, qo = q & 1;
#pragma unroll
        for (int mt = 0; mt < 4; ++mt) {
            int g = 2 * mt + g2;
            int j0 = 6 * g + (qo ? 2 : 0);
            int cnt = qo ? 4 : 2;
            float b0 = sbias[16 * mt + 4 * q + 0];
            float b1 = sbias[16 * mt + 4 * q + 1];
            float b2 = sbias[16 * mt + 4 * q + 2];
            float b3 = sbias[16 * mt + 4 * q + 3];
            float sj[4] = {0.f, 0.f, 0.f, 0.f};
            float qj[4] = {0.f, 0.f, 0.f, 0.f};
#pragma unroll
            for (int nt = 0; nt < 4; ++nt) {
                f32x4 a = acc[mt][nt];
                float a0 = a[0] + b0, a1 = a[1] + b1, a2 = a[2] + b2, a3 = a[3] + b3;
                int n = n0blk + n0w + 16 * nt + lane16;
                float v[4];
                if (!qo) {
                    v[0] = a0 + a1;
                    v[1] = a2 * a3;
                    v[2] = 0.f; v[3] = 0.f;
                } else {
                    v[0] = __sinf(a0);
                    v[1] = __cosf(a1);
                    float e = __expf(-2.f * fabsf(a2));
                    v[2] = copysignf((1.f - e) / (1.f + e), a2);
                    v[3] = a3;
                }
                for (int i = 0; i < cnt; ++i) {
                    imgw[(size_t)(jb48 + j0 + i) * 4096 + n] = (u16)f2bf(v[i]);
                    sj[i] += v[i];
                    qj[i] += v[i] * v[i];
                }
            }
#pragma unroll
            for (int off = 1; off <= 8; off <<= 1) {
#pragma unroll
                for (int i = 0; i < 4; ++i) {
                    sj[i] += __shfl_xor(sj[i], off, 64);
                    qj[i] += __shfl_xor(qj[i], off, 64);
                }
            }
            if (lane16 == 0) {
                for (int i = 0; i < cnt; ++i) {
                    atomicAdd(&gsum[jb48 + j0 + i], sj[i]);
                    atomicAdd(&gss[jb48 + j0 + i],  qj[i]);
                }
            }
        }
    } else {
#pragma unroll
        for (int mt = 0; mt < 3; ++mt) {
            int j0 = 16 * mt + 4 * q;
            float b0 = sbias[64 + j0 + 0];
            float b1 = sbias[64 + j0 + 1];
            float b2 = sbias[64 + j0 + 2];
            float b3 = sbias[64 + j0 + 3];
#pragma unroll
            for (int nt = 0; nt < 4; ++nt) {
                f32x4 a = acc[mt][nt];
                int n = n0blk + n0w + 16 * nt + lane16;
                skipw[(size_t)(jb48 + j0 + 0) * 4096 + n] = (u16)f2bf(a[0] + b0);
                skipw[(size_t)(jb48 + j0 + 1) * 4096 + n] = (u16)f2bf(a[1] + b1);
                skipw[(size_t)(jb48 + j0 + 2) * 4096 + n] = (u16)f2bf(a[2] + b2);
                skipw[(size_t)(jb48 + j0 + 3) * 4096 + n] = (u16)f2bf(a[3] + b3);
            }
        }
    }
}

// ---- K4: finalize: inorm(img) * renorm-chain + skip ----
__global__ __launch_bounds__(256) void k4_final(const u16* __restrict__ imgw,
                                                const u16* __restrict__ skipw,
                                                const float* __restrict__ gsum,
                                                const float* __restrict__ gss,
                                                float* __restrict__ out) {
    int j = blockIdx.x, b = blockIdx.y;
    int bj = b * 48 + j;
    float m = gsum[bj] * (1.f / 4096.f);
    float v = fmaxf(gss[bj] * (1.f / 4096.f) - m * m, 0.f);
    float rs = rsqrtf(v + EPS);
    float g = 1.f;
    float vv = v / (v + EPS);
    for (int k = 0; k < 47 - j; ++k) {
        g *= rsqrtf(vv + EPS);
        vv = vv / (vv + EPS);
    }
    float sc = rs * g;
    const u16* ir = imgw  + (size_t)bj * 4096;
    const u16* sr = skipw + (size_t)bj * 4096;
    float* orow = out + (size_t)bj * 4096;
    int t = threadIdx.x;
#pragma unroll
    for (int i = 0; i < 2; ++i) {
        int idx = t * 8 + i * 2048;
        uint4 iv = *(const uint4*)(ir + idx);
        uint4 sv = *(const uint4*)(sr + idx);
        const u32* ih = (const u32*)&iv;
        const u32* sh = (const u32*)&sv;
        float o[8];
#pragma unroll
        for (int e = 0; e < 4; ++e) {
            float i_lo = bf2f(ih[e] & 0xFFFFu), i_hi = bf2f(ih[e] >> 16);
            float s_lo = bf2f(sh[e] & 0xFFFFu), s_hi = bf2f(sh[e] >> 16);
            o[2 * e]     = (i_lo - m) * sc + s_lo;
            o[2 * e + 1] = (i_hi - m) * sc + s_hi;
        }
        *(float4*)(orow + idx)     = make_float4(o[0], o[1], o[2], o[3]);
        *(float4*)(orow + idx + 4) = make_float4(o[4], o[5], o[6], o[7]);
    }
}

extern "C" void kernel_launch(void* const* d_in, const int* in_sizes, int n_in,
                              void* d_out, int out_size, void* d_ws, size_t ws_size,
                              hipStream_t stream) {
    const float* x   = (const float*)d_in[0];   // [64,256,4096]
    const float* wch = (const float*)d_in[1];   // [64,256]
    const float* wdn = (const float*)d_in[2];   // [48,256]
    float* out = (float*)d_out;                 // [64,48,4096] fp32

    float* gS    = (float*)d_ws;                        // 16384*8 partials
    float* gSS   = gS + 131072;                         // 16384*8
    float* bias  = gSS + 131072;                        // 64*128
    float* gsum  = bias + 64 * 128;                     // 3072
    float* gss   = gsum + 3072;                         // 3072
    u16*   Wc    = (u16*)(gss + 3072);                  // 64*128*256 bf16 (4 MB)
    u16*   xTw   = Wc + (size_t)64 * 128 * 256;         // 64*4096*256 bf16 (134 MB)
    u16*   imgw  = xTw + (size_t)64 * 4096 * 256;       // 64*48*4096 bf16 (25 MB)
    u16*   skipw = imgw + (size_t)64 * 48 * 4096;       // 64*48*4096 bf16 (25 MB)

    k1_tstats<<<dim3(64, 64), dim3(256), 0, stream>>>(x, xTw, gS, gSS);
    k2_prep<<<dim3(64), dim3(256), 0, stream>>>(wch, wdn, gS, gSS, Wc, bias, gsum, gss);
    k3_main<<<dim3(2048), dim3(256), 0, stream>>>(xTw, Wc, bias, imgw, skipw, gsum, gss);
    k4_final<<<dim3(48, 64), dim3(256), 0, stream>>>(imgw, skipw, gsum, gss, out);
}

// Round 6
// 489.608 us; speedup vs baseline: 1.0379x; 1.0379x over previous
//
#include <hip/hip_runtime.h>
#include <hip/hip_bf16.h>

#define EPS 1e-5f

typedef unsigned int u32;
typedef unsigned short u16;
typedef __attribute__((ext_vector_type(8))) short bf16x8;
typedef __attribute__((ext_vector_type(4))) float f32x4;

__device__ __forceinline__ u32 f2bf(float f) {
    u32 u = __float_as_uint(f);
    u += 0x7FFFu + ((u >> 16) & 1u);      // RNE
    return u >> 16;
}
__device__ __forceinline__ float bf2f(u32 h) {
    return __uint_as_float(h << 16);
}

__device__ __forceinline__ void gload16(const void* g, void* l) {
    __builtin_amdgcn_global_load_lds((const __attribute__((address_space(1))) void*)g,
                                     (__attribute__((address_space(3))) void*)l, 16, 0, 0);
}

// ---- K1: fused stats + bf16 transpose ----
// Per-(b,c) partial sums go to indexed slots (no atomics, no zero-init needed).
__global__ __launch_bounds__(256) void k1_tstats(const float* __restrict__ x,
                                                 u16* __restrict__ xT,
                                                 float* __restrict__ gS,
                                                 float* __restrict__ gSS) {
    int b  = blockIdx.y;
    int c0 = (blockIdx.x & 7) * 32;
    int lgrp = blockIdx.x >> 3;
    int l0 = lgrp * 512;
    int t  = threadIdx.x;
    __shared__ __align__(16) u16 T[512 * 32];   // [l][c] bf16, 64 B/row, swizzled slots

    int crow = t >> 3;                          // 0..31 : fixed c-row per thread
    int f4b  = t & 7;
    const float* xr = x + ((size_t)(b * 256 + c0 + crow)) * 4096 + l0;
    int cb   = (2 * crow) & 15;                 // byte-in-slot
    int slot = crow >> 3;                       // logical 16B slot of this c
    float s = 0.f, ss = 0.f;
#pragma unroll
    for (int i = 0; i < 16; ++i) {
        int f4 = f4b + 8 * i;                   // 0..127 float4 within row
        float4 v = *(const float4*)(xr + 4 * f4);
        s  += v.x + v.y + v.z + v.w;
        ss += v.x * v.x + v.y * v.y + v.z * v.z + v.w * v.w;
        char* base = (char*)T + f4 * 256 + (((slot ^ (f4 & 3)) << 4) | cb);
        *(u16*)(base      ) = (u16)f2bf(v.x);
        *(u16*)(base +  64) = (u16)f2bf(v.y);
        *(u16*)(base + 128) = (u16)f2bf(v.z);
        *(u16*)(base + 192) = (u16)f2bf(v.w);
    }
    s += __shfl_xor(s, 1, 64); ss += __shfl_xor(ss, 1, 64);
    s += __shfl_xor(s, 2, 64); ss += __shfl_xor(ss, 2, 64);
    s += __shfl_xor(s, 4, 64); ss += __shfl_xor(ss, 4, 64);
    if ((t & 7) == 0) {
        int idx = ((b * 256 + c0 + crow) << 3) + lgrp;
        gS [idx] = s;
        gSS[idx] = ss;
    }
    __syncthreads();
    u16* xrow = xT + ((size_t)b * 4096 + l0) * 256 + c0;
    int sslot = t & 3;
#pragma unroll
    for (int k = 0; k < 8; ++k) {
        int ll  = k * 64 + (t >> 2);            // 0..511
        int key = (ll >> 2) & 3;
        uint4 vv = *(const uint4*)((const char*)T + ll * 64 + ((sslot ^ key) << 4));
        *(uint4*)(xrow + (size_t)ll * 256 + 8 * sslot) = vv;
    }
}

// ---- K2: softmax-weight prep; 256 blocks (b x 4 j-groups), wch staged via float4 ----
__global__ __launch_bounds__(256) void k2_prep(const float* __restrict__ wch,
                                               const float* __restrict__ wdn,
                                               const float* __restrict__ gS,
                                               const float* __restrict__ gSS,
                                               u16* __restrict__ Wc,
                                               float* __restrict__ bias,
                                               float* __restrict__ gsum,
                                               float* __restrict__ gss) {
    int b = blockIdx.x >> 2, jg = blockIdx.x & 3, t = threadIdx.x;
    __shared__ float swch[64 * 256];            // 64 KB
    __shared__ float sinv[256], ssc[256], smn[256], smxs[256];
#pragma unroll
    for (int k = 0; k < 16; ++k)
        *(float4*)&swch[k * 1024 + t * 4] = *(const float4*)&wch[k * 1024 + t * 4];
    __syncthreads();
    {
        int c = t;
        float mx = -1e30f;
        for (int o = 0; o < 64; ++o) mx = fmaxf(mx, swch[o * 256 + c]);
        float sum = 0.f;
        for (int o = 0; o < 64; ++o) sum += __expf(swch[o * 256 + c] - mx);
        smxs[c] = mx; sinv[c] = 1.f / sum;
        float S = 0.f, Q = 0.f;
#pragma unroll
        for (int k = 0; k < 8; ++k) {
            S += gS [((b * 256 + c) << 3) + k];
            Q += gSS[((b * 256 + c) << 3) + k];
        }
        float m = S * (1.f / 4096.f);
        float v = fmaxf(Q * (1.f / 4096.f) - m * m, 0.f);
        ssc[c] = rsqrtf(v + EPS);
        smn[c] = m;
    }
    __syncthreads();

    int lane = t & 63, w = t >> 6;
    int sub = lane >> 5, li = lane & 31;     // half-wave id, lane-in-half
    int c8 = li * 8;
    u16* Wb = Wc + (size_t)b * 128 * 256;
#pragma unroll
    for (int jj = 0; jj < 4; ++jj) {
        int j = jg * 4 + jj;                 // 0..15
        int r = j * 8 + w * 2 + sub;         // 0..127
        float p = 0.f;
        u32 packed[4];
#pragma unroll
        for (int e = 0; e < 4; ++e) {
            u32 lohi[2];
#pragma unroll
            for (int h = 0; h < 2; ++h) {
                int c = c8 + 2 * e + h;
                float wv;
                if (r < 64)       wv = __expf(swch[r * 256 + c] - smxs[c]) * sinv[c];
                else if (r < 112) wv = wdn[(r - 64) * 256 + c];
                else              wv = 0.f;
                u32 hb = f2bf(wv * ssc[c]);
                lohi[h] = hb;
                p += bf2f(hb) * smn[c];
            }
            packed[e] = lohi[0] | (lohi[1] << 16);
        }
        *(uint4*)&Wb[r * 256 + c8] = *(uint4*)packed;
#pragma unroll
        for (int off = 1; off <= 16; off <<= 1) p += __shfl_xor(p, off, 64);
        if (li == 0) bias[b * 128 + r] = -p;
    }
    if (jg == 0 && t < 48) { gsum[b * 48 + t] = 0.f; gss[b * 48 + t] = 0.f; }
}

// ---- K3: MFMA GEMM, gload_lds staging (pre-swizzled global source) ----
__global__ __launch_bounds__(256, 4) void k3_main(const u16* __restrict__ xT,
                                                  const u16* __restrict__ Wc,
                                                  const float* __restrict__ bias,
                                                  u16* __restrict__ imgw,
                                                  u16* __restrict__ skipw,
                                                  float* __restrict__ gsum,
                                                  float* __restrict__ gss) {
    int lt = blockIdx.x;          // 0..31  (128-wide l tiles)
    int b  = blockIdx.y;          // 0..63
    int n0blk = lt * 128;
    int t = threadIdx.x;
    int w = t >> 6, u = t & 63;
    int lane16 = u & 15, q = u >> 4;
    int m0  = (w & 1) * 64;       // wave m-quadrant
    int n0w = (w >> 1) * 64;      // wave n-quadrant

    __shared__ __align__(16) u16 Wl[128 * 64];   // 16 KB: [row][128B], content slot-swizzled
    __shared__ __align__(16) u16 Xl[128 * 64];   // 16 KB
    __shared__ float sbias[128];

    if (t < 128) sbias[t] = bias[b * 128 + t];

    f32x4 acc[4][4];
#pragma unroll
    for (int mt = 0; mt < 4; ++mt)
#pragma unroll
        for (int nt = 0; nt < 4; ++nt) acc[mt][nt] = (f32x4){0.f, 0.f, 0.f, 0.f};

    const char* Wb = (const char*)(Wc + (size_t)b * 128 * 256);
    const char* xb = (const char*)(xT + ((size_t)b * 4096 + n0blk) * 256);

    // Staging: per wave-call 8 rows x 8 slots of 16B (1 KB), LDS dest linear,
    // global source slot pre-swizzled (slot s ^ (r&7)).
    int r_lane = u >> 3;                    // 0..7
    int gswz   = ((u & 7) ^ r_lane) << 4;   // swizzled 16B-slot byte offset in 128B chunk
    int swz16  = (lane16 & 7) << 4;

    for (int cc = 0; cc < 4; ++cc) {
        if (cc) __syncthreads();
        int c0b = cc << 7;                  // byte offset of 64-c chunk within 512B row
#pragma unroll
        for (int k = 0; k < 4; ++k) {
            int R0 = 32 * w + 8 * k;
            gload16(Wb + (size_t)(R0 + r_lane) * 512 + c0b + gswz, (char*)Wl + R0 * 128);
        }
#pragma unroll
        for (int k = 0; k < 4; ++k) {
            int R0 = 32 * w + 8 * k;
            gload16(xb + (size_t)(R0 + r_lane) * 512 + c0b + gswz, (char*)Xl + R0 * 128);
        }
        __syncthreads();
#pragma unroll
        for (int kk = 0; kk < 2; ++kk) {
            int kob = (kk * 64 + q * 16) ^ swz16;
            bf16x8 af[4], bfr[4];
#pragma unroll
            for (int nt = 0; nt < 4; ++nt)
                bfr[nt] = *(const bf16x8*)((const char*)Xl + (n0w + 16 * nt + lane16) * 128 + kob);
#pragma unroll
            for (int mt = 0; mt < 4; ++mt)
                af[mt] = *(const bf16x8*)((const char*)Wl + (m0 + 16 * mt + lane16) * 128 + kob);
#pragma unroll
            for (int mt = 0; mt < 4; ++mt)
#pragma unroll
                for (int nt = 0; nt < 4; ++nt)
                    acc[mt][nt] = __builtin_amdgcn_mfma_f32_16x16x32_bf16(af[mt], bfr[nt], acc[mt][nt], 0, 0, 0);
        }
    }
    __syncthreads();

    int jb48 = b * 48;
    if (m0 == 0) {
        int g2 = q >> 1, qo = q & 1;
#pragma unroll
        for (int mt = 0; mt < 4; ++mt) {
            int g = 2 * mt + g2;
            int j0 = 6 * g + (qo ? 2 : 0);
            int cnt = qo ? 4 : 2;
            float b0 = sbias[16 * mt + 4 * q + 0];
            float b1 = sbias[16 * mt + 4 * q + 1];
            float b2 = sbias[16 * mt + 4 * q + 2];
            float b3 = sbias[16 * mt + 4 * q + 3];
            float sj[4] = {0.f, 0.f, 0.f, 0.f};
            float qj[4] = {0.f, 0.f, 0.f, 0.f};
#pragma unroll
            for (int nt = 0; nt < 4; ++nt) {
                f32x4 a = acc[mt][nt];
                float a0 = a[0] + b0, a1 = a[1] + b1, a2 = a[2] + b2, a3 = a[3] + b3;
                int n = n0blk + n0w + 16 * nt + lane16;
                float v[4];
                if (!qo) {
                    v[0] = a0 + a1;
                    v[1] = a2 * a3;
                    v[2] = 0.f; v[3] = 0.f;
                } else {
                    v[0] = __sinf(a0);
                    v[1] = __cosf(a1);
                    float e = __expf(-2.f * fabsf(a2));
                    v[2] = copysignf((1.f - e) / (1.f + e), a2);
                    v[3] = a3;
                }
                for (int i = 0; i < cnt; ++i) {
                    imgw[(size_t)(jb48 + j0 + i) * 4096 + n] = (u16)f2bf(v[i]);
                    sj[i] += v[i];
                    qj[i] += v[i] * v[i];
                }
            }
#pragma unroll
            for (int off = 1; off <= 8; off <<= 1) {
#pragma unroll
                for (int i = 0; i < 4; ++i) {
                    sj[i] += __shfl_xor(sj[i], off, 64);
                    qj[i] += __shfl_xor(qj[i], off, 64);
                }
            }
            if (lane16 == 0) {
                for (int i = 0; i < cnt; ++i) {
                    atomicAdd(&gsum[jb48 + j0 + i], sj[i]);
                    atomicAdd(&gss[jb48 + j0 + i],  qj[i]);
                }
            }
        }
    } else {
#pragma unroll
        for (int mt = 0; mt < 3; ++mt) {
            int j0 = 16 * mt + 4 * q;
            float b0 = sbias[64 + j0 + 0];
            float b1 = sbias[64 + j0 + 1];
            float b2 = sbias[64 + j0 + 2];
            float b3 = sbias[64 + j0 + 3];
#pragma unroll
            for (int nt = 0; nt < 4; ++nt) {
                f32x4 a = acc[mt][nt];
                int n = n0blk + n0w + 16 * nt + lane16;
                skipw[(size_t)(jb48 + j0 + 0) * 4096 + n] = (u16)f2bf(a[0] + b0);
                skipw[(size_t)(jb48 + j0 + 1) * 4096 + n] = (u16)f2bf(a[1] + b1);
                skipw[(size_t)(jb48 + j0 + 2) * 4096 + n] = (u16)f2bf(a[2] + b2);
                skipw[(size_t)(jb48 + j0 + 3) * 4096 + n] = (u16)f2bf(a[3] + b3);
            }
        }
    }
}

// ---- K4: finalize: inorm(img) * renorm-chain + skip ----
__global__ __launch_bounds__(256) void k4_final(const u16* __restrict__ imgw,
                                                const u16* __restrict__ skipw,
                                                const float* __restrict__ gsum,
                                                const float* __restrict__ gss,
                                                float* __restrict__ out) {
    int j = blockIdx.x, b = blockIdx.y;
    int bj = b * 48 + j;
    float m = gsum[bj] * (1.f / 4096.f);
    float v = fmaxf(gss[bj] * (1.f / 4096.f) - m * m, 0.f);
    float rs = rsqrtf(v + EPS);
    float g = 1.f;
    float vv = v / (v + EPS);
    for (int k = 0; k < 47 - j; ++k) {
        g *= rsqrtf(vv + EPS);
        vv = vv / (vv + EPS);
    }
    float sc = rs * g;
    const u16* ir = imgw  + (size_t)bj * 4096;
    const u16* sr = skipw + (size_t)bj * 4096;
    float* orow = out + (size_t)bj * 4096;
    int t = threadIdx.x;
#pragma unroll
    for (int i = 0; i < 2; ++i) {
        int idx = t * 8 + i * 2048;
        uint4 iv = *(const uint4*)(ir + idx);
        uint4 sv = *(const uint4*)(sr + idx);
        const u32* ih = (const u32*)&iv;
        const u32* sh = (const u32*)&sv;
        float o[8];
#pragma unroll
        for (int e = 0; e < 4; ++e) {
            float i_lo = bf2f(ih[e] & 0xFFFFu), i_hi = bf2f(ih[e] >> 16);
            float s_lo = bf2f(sh[e] & 0xFFFFu), s_hi = bf2f(sh[e] >> 16);
            o[2 * e]     = (i_lo - m) * sc + s_lo;
            o[2 * e + 1] = (i_hi - m) * sc + s_hi;
        }
        *(float4*)(orow + idx)     = make_float4(o[0], o[1], o[2], o[3]);
        *(float4*)(orow + idx + 4) = make_float4(o[4], o[5], o[6], o[7]);
    }
}

extern "C" void kernel_launch(void* const* d_in, const int* in_sizes, int n_in,
                              void* d_out, int out_size, void* d_ws, size_t ws_size,
                              hipStream_t stream) {
    const float* x   = (const float*)d_in[0];   // [64,256,4096]
    const float* wch = (const float*)d_in[1];   // [64,256]
    const float* wdn = (const float*)d_in[2];   // [48,256]
    float* out = (float*)d_out;                 // [64,48,4096] fp32

    float* gS    = (float*)d_ws;                        // 16384*8 partials
    float* gSS   = gS + 131072;                         // 16384*8
    float* bias  = gSS + 131072;                        // 64*128
    float* gsum  = bias + 64 * 128;                     // 3072
    float* gss   = gsum + 3072;                         // 3072
    u16*   Wc    = (u16*)(gss + 3072);                  // 64*128*256 bf16 (4 MB)
    u16*   xTw   = Wc + (size_t)64 * 128 * 256;         // 64*4096*256 bf16 (134 MB)
    u16*   imgw  = xTw + (size_t)64 * 4096 * 256;       // 64*48*4096 bf16 (25 MB)
    u16*   skipw = imgw + (size_t)64 * 48 * 4096;       // 64*48*4096 bf16 (25 MB)

    k1_tstats<<<dim3(64, 64), dim3(256), 0, stream>>>(x, xTw, gS, gSS);
    k2_prep<<<dim3(256), dim3(256), 0, stream>>>(wch, wdn, gS, gSS, Wc, bias, gsum, gss);
    k3_main<<<dim3(32, 64), dim3(256), 0, stream>>>(xTw, Wc, bias, imgw, skipw, gsum, gss);
    k4_final<<<dim3(48, 64), dim3(256), 0, stream>>>(imgw, skipw, gsum, gss, out);
}